// Round 20
// baseline (128.730 us; speedup 1.0000x reference)
//
#include <hip/hip_runtime.h>
#include <hip/hip_fp16.h>

// GAT regression: 2-layer GAT + linear head.
// R27: scatter SVPT 16->32 (202 blocks): halves per-bucket atomic rounds,
//      per-(block,bucket) runs ~42 entries (~168B) -> mostly full-line entry
//      writes (amplification ~1.4x vs 2.6x at VPT8). Staging packed as
//      bl = b|(l<<16) + pk (~80 VGPR, no spill).
// R26 retained: agg1 = R24 2-edges-per-wave-load on row-major fp8 128B rows
//      (43us; 8 schedule variants confirm random-gather structural floor),
//      csr_build@1024, fused D1/D2, local bucket scans, u16 eps, gemm2
//      deleted (projections in agg1 epilogue), MFMA gemm1, scalar agg2.
// Requires N < 65536 (16-bit packing). N = 50000.

#define LEAKY(x) ((x) > 0.f ? (x) : 0.2f * (x))

typedef float v2f __attribute__((ext_vector_type(2)));
typedef _Float16 f16x8 __attribute__((ext_vector_type(8)));
typedef __fp16 h16x2 __attribute__((ext_vector_type(2)));
typedef float f32x4 __attribute__((ext_vector_type(4)));

// ---------------- D0: zero control arrays ----------------

__global__ __launch_bounds__(256) void zero_kernel(int* __restrict__ bcnt,
                                                   int* __restrict__ bcur_rel,
                                                   int* __restrict__ off,
                                                   int B, int n, int Etot) {
  if (threadIdx.x <= (unsigned)B) {
    bcnt[threadIdx.x] = 0;
    bcur_rel[threadIdx.x] = 0;
  }
  if (threadIdx.x == 255) off[n] = Etot;
}

// ---------------- D1: wprep + bucket_cnt (fused, disjoint blocks) -----------

template <int VPT>
__global__ __launch_bounds__(256) void prep_cnt_kernel(const float* __restrict__ W1,
                                                       const float* __restrict__ W2,
                                                       const float* __restrict__ as2,
                                                       const float* __restrict__ ad2,
                                                       const float* __restrict__ lw,
                                                       unsigned short* __restrict__ Wp1,
                                                       float* __restrict__ vsrc2,
                                                       float* __restrict__ vdst2,
                                                       float* __restrict__ vlin,
                                                       const int* __restrict__ ei, int E, int n,
                                                       int* __restrict__ bc, int WB) {
  if ((int)blockIdx.x < WB) {
    int t = blockIdx.x * 256 + threadIdx.x;
    if (t < 16384) {
      int e = t;
      int i = e & 7;
      int c = (e >> 3) & 15;
      int g = (e >> 7) & 3;
      int kk = (e >> 9) & 3;
      int cn = e >> 11;
      int k = kk * 32 + g * 8 + i;
      int col = cn * 16 + c;
      __half h = __float2half(W1[k * 128 + col]);
      Wp1[e] = *(unsigned short*)&h;
    } else if (t < 16384 + 128) {
      int k = t - 16384;
      float a = 0.f, b = 0.f, s = 0.f;
      for (int cc = 0; cc < 64; ++cc) {
        float w = W2[k * 64 + cc];
        a = fmaf(w, as2[cc], a);
        b = fmaf(w, ad2[cc], b);
        s = fmaf(w, lw[cc], s);
      }
      vsrc2[k] = a;
      vdst2[k] = b;
      vlin[k] = s;
    }
    return;
  }
  // ---- bucket_cnt part ----
  __shared__ int lc[256];
  int t = threadIdx.x;
  lc[t] = 0;
  __syncthreads();
  int base = (blockIdx.x - WB) * (256 * VPT) + t;
  int tot = E + n;
#pragma unroll
  for (int u = 0; u < VPT; ++u) {
    int i = base + u * 256;
    if (i < tot) {
      int d = (i < E) ? ei[E + i] : (i - E);
      atomicAdd(&lc[d >> 8], 1);
    }
  }
  __syncthreads();
  if (lc[t]) atomicAdd(&bc[t], lc[t]);
}

// ---------------- D2: gemm1 + bucket_scatter (fused, concurrent) ------------

template <int SVPT>
__global__ __launch_bounds__(256) void gemm_scatter_kernel(
    const float* __restrict__ X, const uint4* __restrict__ Wp,
    const float* __restrict__ a_src, const float* __restrict__ a_dst,
    unsigned char* __restrict__ Hout, float2* __restrict__ als, float2* __restrict__ ald,
    const int* __restrict__ ei, int E, int n,
    const int* __restrict__ bcnt, int* __restrict__ bcur_rel,
    unsigned* __restrict__ entries, int B, int GB) {
  if ((int)blockIdx.x < GB) {
    // ================= gemm1 =================
    __shared__ float Xl[32 * 132];
    __shared__ float lgt[2][2][2][16];
    int t = threadIdx.x;
    int wave = t >> 6, lane = t & 63;
    int wm = wave >> 1, wn = wave & 1;
    int g = lane >> 4, c = lane & 15;
    int nb0 = blockIdx.x * 32;

    {
      const float4* Xg = (const float4*)X;
      float4* Xs = (float4*)Xl;
#pragma unroll
      for (int u = 0; u < 4; ++u) {
        int idx = u * 256 + t;
        int r = idx >> 5, c4 = idx & 31;
        int row = nb0 + r;
        int rc = row < n ? row : (n - 1);
        Xs[r * 33 + c4] = Xg[(size_t)rc * 32 + c4];
      }
    }
    __syncthreads();

    f16x8 af[4];
    const float* xr = Xl + (wm * 16 + c) * 132 + g * 8;
#pragma unroll
    for (int kk = 0; kk < 4; ++kk) {
      float4 x0 = *(const float4*)(xr + kk * 32);
      float4 x1 = *(const float4*)(xr + kk * 32 + 4);
      union { f16x8 v; h16x2 p[4]; } A;
      A.p[0] = __builtin_amdgcn_cvt_pkrtz(x0.x, x0.y);
      A.p[1] = __builtin_amdgcn_cvt_pkrtz(x0.z, x0.w);
      A.p[2] = __builtin_amdgcn_cvt_pkrtz(x1.x, x1.y);
      A.p[3] = __builtin_amdgcn_cvt_pkrtz(x1.z, x1.w);
      af[kk] = A.v;
    }

    f32x4 acc[4];
    f32x4 z = {0.f, 0.f, 0.f, 0.f};
#pragma unroll
    for (int cn = 0; cn < 4; ++cn) acc[cn] = z;
#pragma unroll
    for (int cn = 0; cn < 4; ++cn) {
      int cng = wn * 4 + cn;
#pragma unroll
      for (int kk = 0; kk < 4; ++kk) {
        union { uint4 u; f16x8 v; } Bf;
        Bf.u = Wp[(cng * 4 + kk) * 64 + lane];
        acc[cn] = __builtin_amdgcn_mfma_f32_16x16x32_f16(af[kk], Bf.v, acc[cn], 0, 0, 0);
      }
    }

    float asv[4], adv[4];
#pragma unroll
    for (int cn = 0; cn < 4; ++cn) {
      int col_l = wn * 64 + cn * 16 + c;
      asv[cn] = a_src[col_l];
      adv[cn] = a_dst[col_l];
    }
    float ps[4] = {0.f, 0.f, 0.f, 0.f};
    float pd[4] = {0.f, 0.f, 0.f, 0.f};
#pragma unroll
    for (int cn = 0; cn < 4; ++cn) {
#pragma unroll
      for (int r = 0; r < 4; ++r) {
        float v = acc[cn][r];
        ps[r] = fmaf(v, asv[cn], ps[r]);
        pd[r] = fmaf(v, adv[cn], pd[r]);
        int noder = nb0 + wm * 16 + g * 4 + r;
        int colg = wn * 64 + cn * 16 + c;
        if (noder < n) {
          int b8 = __builtin_amdgcn_cvt_pk_fp8_f32(v, v, 0, false);
          Hout[(size_t)noder * 128 + colg] = (unsigned char)(b8 & 0xff);
        }
      }
    }
#pragma unroll
    for (int r = 0; r < 4; ++r) {
#pragma unroll
      for (int m = 1; m <= 8; m <<= 1) {
        ps[r] += __shfl_xor(ps[r], m, 64);
        pd[r] += __shfl_xor(pd[r], m, 64);
      }
    }
    if (c == 0) {
#pragma unroll
      for (int r = 0; r < 4; ++r) {
        lgt[wm][wn][0][g * 4 + r] = ps[r];
        lgt[wm][wn][1][g * 4 + r] = pd[r];
      }
    }
    __syncthreads();
    if (t < 32) {
      int wmm = t >> 4, row = t & 15;
      int node = nb0 + wmm * 16 + row;
      if (node < n) {
        als[node] = make_float2(lgt[wmm][0][0][row], lgt[wmm][1][0][row]);
        ald[node] = make_float2(lgt[wmm][0][1][row], lgt[wmm][1][1][row]);
      }
    }
    return;
  }
  // ================= bucket_scatter (SVPT edges/thread, packed staging) =====
  __shared__ int lc[256];
  __shared__ int lbase[256];
  __shared__ int bscan[256];
  int t = threadIdx.x;
  lc[t] = 0;
  int v = (t < B) ? bcnt[t] : 0;
  bscan[t] = v;
  __syncthreads();
  for (int s = 1; s < 256; s <<= 1) {
    int a = (t >= s) ? bscan[t - s] : 0;
    __syncthreads();
    bscan[t] += a;
    __syncthreads();
  }
  int excl = bscan[t] - v;

  int base = (blockIdx.x - GB) * (256 * SVPT) + t;
  int tot = E + n;
  int bl[SVPT];
  unsigned pk[SVPT];
#pragma unroll
  for (int u = 0; u < SVPT; ++u) {
    int i = base + u * 256;
    bl[u] = -1;
    if (i < tot) {
      int s, d;
      if (i < E) { s = ei[i]; d = ei[E + i]; }
      else       { s = d = i - E; }
      int b = d >> 8;
      int l = atomicAdd(&lc[b], 1);
      bl[u] = b | (l << 16);
      pk[u] = (unsigned)s | ((unsigned)(d & 255) << 16);
    }
  }
  __syncthreads();
  if (lc[t]) lbase[t] = excl + atomicAdd(&bcur_rel[t], lc[t]);
  __syncthreads();
#pragma unroll
  for (int u = 0; u < SVPT; ++u)
    if (bl[u] >= 0) entries[lbase[bl[u] & 0xffff] + (bl[u] >> 16)] = pk[u];
}

// ---------------- D3: csr_build at 1024 threads ----------------

__global__ __launch_bounds__(1024) void csr_build_kernel(const unsigned* __restrict__ entries,
                                                         const int* __restrict__ bcnt,
                                                         int* __restrict__ off,
                                                         unsigned short* __restrict__ eps,
                                                         int n, int B) {
  __shared__ int bscan[256];
  __shared__ int hist[256];
  __shared__ int scn[256];
  __shared__ int cur[256];
  int b = blockIdx.x, t = threadIdx.x;
  if (t < 256) bscan[t] = (t < B) ? bcnt[t] : 0;
  __syncthreads();
  for (int s = 1; s < 256; s <<= 1) {
    int a = (t >= (unsigned)s && t < 256) ? bscan[t - s] : 0;
    __syncthreads();
    if (t < 256) bscan[t] += a;
    __syncthreads();
  }
  int k0 = (b == 0) ? 0 : bscan[b - 1];
  int k1 = bscan[b];

  if (t < 256) hist[t] = 0;
  __syncthreads();
  for (int k = k0 + t; k < k1; k += 1024) atomicAdd(&hist[(entries[k] >> 16) & 255], 1);
  __syncthreads();
  int hv = (t < 256) ? hist[t] : 0;
  if (t < 256) scn[t] = hv;
  __syncthreads();
  for (int s = 1; s < 256; s <<= 1) {
    int a = (t >= (unsigned)s && t < 256) ? scn[t - s] : 0;
    __syncthreads();
    if (t < 256) scn[t] += a;
    __syncthreads();
  }
  if (t < 256) {
    int excl = scn[t] - hv;
    int d = (b << 8) + t;
    if (d < n) off[d] = k0 + excl;
    cur[t] = k0 + excl;
  }
  __syncthreads();
  for (int k = k0 + t; k < k1; k += 1024) {
    unsigned e = entries[k];
    unsigned dl = (e >> 16) & 255;
    int p = atomicAdd(&cur[dl], 1);
    eps[p] = (unsigned short)(e & 0xffffu);
  }
}

// ---------------- D4: agg1 (2 edges per wave-load, R24) ----------------

__global__ __launch_bounds__(256) void agg1_kernel(const unsigned char* __restrict__ Hb8,
                                                   const float2* __restrict__ als,
                                                   const float2* __restrict__ ald,
                                                   const unsigned short* __restrict__ eps,
                                                   const int* __restrict__ off,
                                                   const float* __restrict__ b1,
                                                   const float* __restrict__ vsrc2,
                                                   const float* __restrict__ vdst2,
                                                   const float* __restrict__ vlin,
                                                   float2* __restrict__ gsrc,
                                                   float* __restrict__ adst2, int n) {
  __shared__ float wlds[4][128];
  int wid = (blockIdx.x * 256 + threadIdx.x) >> 6;
  int lane = threadIdx.x & 63;
  if (wid >= n) return;
  wid = __builtin_amdgcn_readfirstlane(wid);
  int wslot = (threadIdx.x >> 6) & 3;
  int sel = lane >> 5;      // which edge of the pair this half-wave handles
  int c31 = lane & 31;      // dword (4 fp8 ch) within the row
  int head = c31 >> 4;      // head of these channels
  int k0 = off[wid], k1 = off[wid + 1];
  const unsigned* Hd = (const unsigned*)Hb8;  // row = 32 dwords
  float2 advv = ald[wid];
  int wbase = head * 64 + sel;  // LDS weight index base

  float a0 = 0.f, a1 = 0.f, a2 = 0.f, a3 = 0.f, den0 = 0.f, den1 = 0.f;

  for (int kb = k0; kb < k1; kb += 64) {
    int rem = min(k1 - kb, 64);
    int e = kb + (lane < rem ? lane : rem - 1);
    unsigned pp = eps[e];
    float2 l = als[pp];
    float g0 = __expf(LEAKY(l.x + advv.x));
    float g1 = __expf(LEAKY(l.y + advv.y));
    bool ok = lane < rem;
    wlds[wslot][lane] = ok ? g0 : 0.f;       // phantom edges get w = 0
    wlds[wslot][64 + lane] = ok ? g1 : 0.f;
    if (ok) { den0 += g0; den1 += g1; }
    int npair = (rem + 1) >> 1;

#define PAIR1(qq)                                                                   \
  {                                                                                 \
    unsigned p = (unsigned)__shfl((int)pp, ((qq) << 1) + sel, 64);                  \
    float w = wlds[wslot][wbase + ((qq) << 1)];                                     \
    unsigned hv = Hd[p * 32u + (unsigned)c31];                                      \
    v2f lo = __builtin_amdgcn_cvt_pk_f32_fp8((int)hv, false);                       \
    v2f hi = __builtin_amdgcn_cvt_pk_f32_fp8((int)hv, true);                        \
    a0 = fmaf(lo.x, w, a0);                                                         \
    a1 = fmaf(lo.y, w, a1);                                                         \
    a2 = fmaf(hi.x, w, a2);                                                         \
    a3 = fmaf(hi.y, w, a3);                                                         \
  }

    int nb = npair >> 3;
    for (int b = 0; b < nb; ++b) {
      int qb = b << 3;
#pragma unroll
      for (int q = 0; q < 8; ++q) PAIR1(qb + q);
    }
    for (int q = nb << 3; q < npair; ++q) PAIR1(q);
#undef PAIR1
  }

  // merge the two edge-sets (halves computed disjoint edges, same channels)
  a0 += __shfl_xor(a0, 32, 64);
  a1 += __shfl_xor(a1, 32, 64);
  a2 += __shfl_xor(a2, 32, 64);
  a3 += __shfl_xor(a3, 32, 64);
  // den butterfly (per-lane partials over distinct edges)
#pragma unroll
  for (int m = 1; m <= 32; m <<= 1) {
    den0 += __shfl_xor(den0, m, 64);
    den1 += __shfl_xor(den1, m, 64);
  }
  float den = head ? den1 : den0;

  // elu(out + b1), then project onto the three layer-2 vectors (4 ch/lane).
  float inv = 1.f / (den + 1e-16f);
  float4 bv = ((const float4*)b1)[c31];
  float r0 = a0 * inv + bv.x;
  float r1 = a1 * inv + bv.y;
  float r2 = a2 * inv + bv.z;
  float r3 = a3 * inv + bv.w;
  r0 = r0 > 0.f ? r0 : (__expf(r0) - 1.f);
  r1 = r1 > 0.f ? r1 : (__expf(r1) - 1.f);
  r2 = r2 > 0.f ? r2 : (__expf(r2) - 1.f);
  r3 = r3 > 0.f ? r3 : (__expf(r3) - 1.f);
  float4 vs = ((const float4*)vsrc2)[c31];
  float4 vd = ((const float4*)vdst2)[c31];
  float4 vl = ((const float4*)vlin)[c31];
  float ps = r0 * vs.x + r1 * vs.y + r2 * vs.z + r3 * vs.w;
  float pd = r0 * vd.x + r1 * vd.y + r2 * vd.z + r3 * vd.w;
  float sv = r0 * vl.x + r1 * vl.y + r2 * vl.z + r3 * vl.w;
  // channels live once per 32-lane half (halves duplicate) -> xor 1..16 only
#pragma unroll
  for (int m = 1; m <= 16; m <<= 1) {
    ps += __shfl_xor(ps, m, 64);
    pd += __shfl_xor(pd, m, 64);
    sv += __shfl_xor(sv, m, 64);
  }
  if (lane == 0) {
    gsrc[wid] = make_float2(ps, sv);
    adst2[wid] = pd;
  }
}

// ---------------- D5: agg2 ----------------

__global__ __launch_bounds__(256) void agg2_kernel(const float2* __restrict__ gsrc,
                                                   const float* __restrict__ adst2,
                                                   const unsigned short* __restrict__ eps,
                                                   const int* __restrict__ off,
                                                   const float* __restrict__ b2,
                                                   const float* __restrict__ lin_w,
                                                   const float* __restrict__ lin_b,
                                                   float* __restrict__ out, int n) {
  int wid = (blockIdx.x * 256 + threadIdx.x) >> 6;
  int lane = threadIdx.x & 63;
  if (wid >= n) return;
  wid = __builtin_amdgcn_readfirstlane(wid);
  int k0 = off[wid], k1 = off[wid + 1];
  float adv = adst2[wid];

  float num = 0.f, den = 0.f;
  for (int kb = k0; kb < k1; kb += 64) {
    int e = kb + lane;
    bool ok = e < k1;
    unsigned pp = eps[ok ? e : k0];
    float2 g = gsrc[pp];
    float w = ok ? __expf(LEAKY(g.x + adv)) : 0.f;
    num = fmaf(w, g.y, num);
    den += w;
  }
  float bt = b2[lane] * lin_w[lane];
#pragma unroll
  for (int m = 1; m <= 32; m <<= 1) {
    num += __shfl_xor(num, m, 64);
    den += __shfl_xor(den, m, 64);
    bt  += __shfl_xor(bt, m, 64);
  }
  if (lane == 0) out[wid] = num / (den + 1e-16f) + bt + lin_b[0];
}

// ---------------- launcher ----------------

static inline size_t alignup(size_t v) { return (v + 255) & ~(size_t)255; }

extern "C" void kernel_launch(void* const* d_in, const int* in_sizes, int n_in,
                              void* d_out, int out_size, void* d_ws, size_t ws_size,
                              hipStream_t stream) {
  const float* x   = (const float*)d_in[0];
  const int*   ei  = (const int*)d_in[1];
  const float* W1  = (const float*)d_in[2];
  const float* as1 = (const float*)d_in[3];
  const float* ad1 = (const float*)d_in[4];
  const float* b1  = (const float*)d_in[5];
  const float* W2  = (const float*)d_in[6];
  const float* as2 = (const float*)d_in[7];
  const float* ad2 = (const float*)d_in[8];
  const float* b2  = (const float*)d_in[9];
  const float* lw  = (const float*)d_in[10];
  const float* lb  = (const float*)d_in[11];
  float* out = (float*)d_out;

  const int N = out_size;          // 50000
  const int E = in_sizes[1] / 2;   // 1600000
  const int Etot = E + N;
  const int B = (N + 255) >> 8;    // 196 buckets

  char* p = (char*)d_ws;
  int* bcnt = (int*)p;  p += alignup((size_t)(B + 1) * 4);
  int* bcur_rel = (int*)p; p += alignup((size_t)(B + 1) * 4);
  unsigned* entries = (unsigned*)p; p += alignup((size_t)Etot * 4);
  int* off  = (int*)p;  p += alignup((size_t)(N + 1) * 4);
  unsigned short* eps = (unsigned short*)p; p += alignup((size_t)Etot * 2);
  float2* als = (float2*)p; p += alignup((size_t)N * 8);
  float2* ald = (float2*)p; p += alignup((size_t)N * 8);
  float2* gsrc = (float2*)p; p += alignup((size_t)N * 8);
  float* adst2 = (float*)p; p += alignup((size_t)N * 4);
  unsigned char* h1b = (unsigned char*)p; p += alignup((size_t)N * 128);
  unsigned short* wp1 = (unsigned short*)p; p += alignup((size_t)16384 * 2);
  float* vsrc2 = (float*)p; p += alignup((size_t)128 * 4);
  float* vdst2 = (float*)p; p += alignup((size_t)128 * 4);
  float* vlin  = (float*)p; p += alignup((size_t)128 * 4);

  constexpr int VPT = 8;    // bucket_cnt edges/thread
  constexpr int SVPT = 32;  // bucket_scatter edges/thread
  int egrid = (Etot + 256 * VPT - 1) / (256 * VPT);
  int sgrid = (Etot + 256 * SVPT - 1) / (256 * SVPT);
  constexpr int WB = 65;                 // wprep blocks
  int GB = (N + 31) / 32;                // gemm1 blocks

  zero_kernel<<<1, 256, 0, stream>>>(bcnt, bcur_rel, off, B, N, Etot);
  prep_cnt_kernel<VPT><<<WB + egrid, 256, 0, stream>>>(
      W1, W2, as2, ad2, lw, wp1, vsrc2, vdst2, vlin, ei, E, N, bcnt, WB);
  gemm_scatter_kernel<SVPT><<<GB + sgrid, 256, 0, stream>>>(
      x, (const uint4*)wp1, as1, ad1, h1b, als, ald,
      ei, E, N, bcnt, bcur_rel, entries, B, GB);
  csr_build_kernel<<<B, 1024, 0, stream>>>(entries, bcnt, off, eps, N, B);

  agg1_kernel<<<(N + 3) / 4, 256, 0, stream>>>(h1b, als, ald, eps, off, b1,
                                               vsrc2, vdst2, vlin, gsrc, adst2, N);
  agg2_kernel<<<(N + 3) / 4, 256, 0, stream>>>(gsrc, adst2, eps, off, b2, lw, lb, out, N);
}

// Round 21
// 124.646 us; speedup vs baseline: 1.0328x; 1.0328x over previous
//
#include <hip/hip_runtime.h>
#include <hip/hip_fp16.h>

// GAT regression: 2-layer GAT + linear head.
// R28: REVERT to R26 exactly (best measured: 125.1us). R27's SVPT=32 staging
//      (+3.6us) cut scatter occupancy (64+ staging VGPR) and halved block
//      parallelism. VPT sweep: 8 -> ~41us, 16 -> ~35us (best), 32 -> ~38us.
// Final structure: zero | prep(Wpack+v-vectors)+bucket_cnt | gemm1(MFMA,
//      LDS-staged A, fp8 H rows)+bucket_scatter | csr_build@1024 (u16 eps) |
//      agg1 (2 edges/wave-load, in-agg softmax, fused layer-2 projections) |
//      agg2 (scalar (logit,s) aggregation + head).
// agg1 pinned at ~43us across 8+ variants: random-gather latency floor on
// the 6.4MB fp8 H table. Requires N < 65536 (16-bit packing). N = 50000.

#define LEAKY(x) ((x) > 0.f ? (x) : 0.2f * (x))

typedef float v2f __attribute__((ext_vector_type(2)));
typedef _Float16 f16x8 __attribute__((ext_vector_type(8)));
typedef __fp16 h16x2 __attribute__((ext_vector_type(2)));
typedef float f32x4 __attribute__((ext_vector_type(4)));

// ---------------- D0: zero control arrays ----------------

__global__ __launch_bounds__(256) void zero_kernel(int* __restrict__ bcnt,
                                                   int* __restrict__ bcur_rel,
                                                   int* __restrict__ off,
                                                   int B, int n, int Etot) {
  if (threadIdx.x <= (unsigned)B) {
    bcnt[threadIdx.x] = 0;
    bcur_rel[threadIdx.x] = 0;
  }
  if (threadIdx.x == 255) off[n] = Etot;
}

// ---------------- D1: wprep + bucket_cnt (fused, disjoint blocks) -----------

template <int VPT>
__global__ __launch_bounds__(256) void prep_cnt_kernel(const float* __restrict__ W1,
                                                       const float* __restrict__ W2,
                                                       const float* __restrict__ as2,
                                                       const float* __restrict__ ad2,
                                                       const float* __restrict__ lw,
                                                       unsigned short* __restrict__ Wp1,
                                                       float* __restrict__ vsrc2,
                                                       float* __restrict__ vdst2,
                                                       float* __restrict__ vlin,
                                                       const int* __restrict__ ei, int E, int n,
                                                       int* __restrict__ bc, int WB) {
  if ((int)blockIdx.x < WB) {
    int t = blockIdx.x * 256 + threadIdx.x;
    if (t < 16384) {
      int e = t;
      int i = e & 7;
      int c = (e >> 3) & 15;
      int g = (e >> 7) & 3;
      int kk = (e >> 9) & 3;
      int cn = e >> 11;
      int k = kk * 32 + g * 8 + i;
      int col = cn * 16 + c;
      __half h = __float2half(W1[k * 128 + col]);
      Wp1[e] = *(unsigned short*)&h;
    } else if (t < 16384 + 128) {
      int k = t - 16384;
      float a = 0.f, b = 0.f, s = 0.f;
      for (int cc = 0; cc < 64; ++cc) {
        float w = W2[k * 64 + cc];
        a = fmaf(w, as2[cc], a);
        b = fmaf(w, ad2[cc], b);
        s = fmaf(w, lw[cc], s);
      }
      vsrc2[k] = a;
      vdst2[k] = b;
      vlin[k] = s;
    }
    return;
  }
  // ---- bucket_cnt part ----
  __shared__ int lc[256];
  int t = threadIdx.x;
  lc[t] = 0;
  __syncthreads();
  int base = (blockIdx.x - WB) * (256 * VPT) + t;
  int tot = E + n;
#pragma unroll
  for (int u = 0; u < VPT; ++u) {
    int i = base + u * 256;
    if (i < tot) {
      int d = (i < E) ? ei[E + i] : (i - E);
      atomicAdd(&lc[d >> 8], 1);
    }
  }
  __syncthreads();
  if (lc[t]) atomicAdd(&bc[t], lc[t]);
}

// ---------------- D2: gemm1 + bucket_scatter (fused, concurrent) ------------

template <int SVPT>
__global__ __launch_bounds__(256) void gemm_scatter_kernel(
    const float* __restrict__ X, const uint4* __restrict__ Wp,
    const float* __restrict__ a_src, const float* __restrict__ a_dst,
    unsigned char* __restrict__ Hout, float2* __restrict__ als, float2* __restrict__ ald,
    const int* __restrict__ ei, int E, int n,
    const int* __restrict__ bcnt, int* __restrict__ bcur_rel,
    unsigned* __restrict__ entries, int B, int GB) {
  if ((int)blockIdx.x < GB) {
    // ================= gemm1 =================
    __shared__ float Xl[32 * 132];
    __shared__ float lgt[2][2][2][16];
    int t = threadIdx.x;
    int wave = t >> 6, lane = t & 63;
    int wm = wave >> 1, wn = wave & 1;
    int g = lane >> 4, c = lane & 15;
    int nb0 = blockIdx.x * 32;

    {
      const float4* Xg = (const float4*)X;
      float4* Xs = (float4*)Xl;
#pragma unroll
      for (int u = 0; u < 4; ++u) {
        int idx = u * 256 + t;
        int r = idx >> 5, c4 = idx & 31;
        int row = nb0 + r;
        int rc = row < n ? row : (n - 1);
        Xs[r * 33 + c4] = Xg[(size_t)rc * 32 + c4];
      }
    }
    __syncthreads();

    f16x8 af[4];
    const float* xr = Xl + (wm * 16 + c) * 132 + g * 8;
#pragma unroll
    for (int kk = 0; kk < 4; ++kk) {
      float4 x0 = *(const float4*)(xr + kk * 32);
      float4 x1 = *(const float4*)(xr + kk * 32 + 4);
      union { f16x8 v; h16x2 p[4]; } A;
      A.p[0] = __builtin_amdgcn_cvt_pkrtz(x0.x, x0.y);
      A.p[1] = __builtin_amdgcn_cvt_pkrtz(x0.z, x0.w);
      A.p[2] = __builtin_amdgcn_cvt_pkrtz(x1.x, x1.y);
      A.p[3] = __builtin_amdgcn_cvt_pkrtz(x1.z, x1.w);
      af[kk] = A.v;
    }

    f32x4 acc[4];
    f32x4 z = {0.f, 0.f, 0.f, 0.f};
#pragma unroll
    for (int cn = 0; cn < 4; ++cn) acc[cn] = z;
#pragma unroll
    for (int cn = 0; cn < 4; ++cn) {
      int cng = wn * 4 + cn;
#pragma unroll
      for (int kk = 0; kk < 4; ++kk) {
        union { uint4 u; f16x8 v; } Bf;
        Bf.u = Wp[(cng * 4 + kk) * 64 + lane];
        acc[cn] = __builtin_amdgcn_mfma_f32_16x16x32_f16(af[kk], Bf.v, acc[cn], 0, 0, 0);
      }
    }

    float asv[4], adv[4];
#pragma unroll
    for (int cn = 0; cn < 4; ++cn) {
      int col_l = wn * 64 + cn * 16 + c;
      asv[cn] = a_src[col_l];
      adv[cn] = a_dst[col_l];
    }
    float ps[4] = {0.f, 0.f, 0.f, 0.f};
    float pd[4] = {0.f, 0.f, 0.f, 0.f};
#pragma unroll
    for (int cn = 0; cn < 4; ++cn) {
#pragma unroll
      for (int r = 0; r < 4; ++r) {
        float v = acc[cn][r];
        ps[r] = fmaf(v, asv[cn], ps[r]);
        pd[r] = fmaf(v, adv[cn], pd[r]);
        int noder = nb0 + wm * 16 + g * 4 + r;
        int colg = wn * 64 + cn * 16 + c;
        if (noder < n) {
          int b8 = __builtin_amdgcn_cvt_pk_fp8_f32(v, v, 0, false);
          Hout[(size_t)noder * 128 + colg] = (unsigned char)(b8 & 0xff);
        }
      }
    }
#pragma unroll
    for (int r = 0; r < 4; ++r) {
#pragma unroll
      for (int m = 1; m <= 8; m <<= 1) {
        ps[r] += __shfl_xor(ps[r], m, 64);
        pd[r] += __shfl_xor(pd[r], m, 64);
      }
    }
    if (c == 0) {
#pragma unroll
      for (int r = 0; r < 4; ++r) {
        lgt[wm][wn][0][g * 4 + r] = ps[r];
        lgt[wm][wn][1][g * 4 + r] = pd[r];
      }
    }
    __syncthreads();
    if (t < 32) {
      int wmm = t >> 4, row = t & 15;
      int node = nb0 + wmm * 16 + row;
      if (node < n) {
        als[node] = make_float2(lgt[wmm][0][0][row], lgt[wmm][1][0][row]);
        ald[node] = make_float2(lgt[wmm][0][1][row], lgt[wmm][1][1][row]);
      }
    }
    return;
  }
  // ================= bucket_scatter (SVPT edges/thread) =================
  __shared__ int lc[256];
  __shared__ int lbase[256];
  __shared__ int bscan[256];
  int t = threadIdx.x;
  lc[t] = 0;
  int v = (t < B) ? bcnt[t] : 0;
  bscan[t] = v;
  __syncthreads();
  for (int s = 1; s < 256; s <<= 1) {
    int a = (t >= s) ? bscan[t - s] : 0;
    __syncthreads();
    bscan[t] += a;
    __syncthreads();
  }
  int excl = bscan[t] - v;

  int base = (blockIdx.x - GB) * (256 * SVPT) + t;
  int tot = E + n;
  int bb[SVPT], ll[SVPT];
  unsigned pk[SVPT];
#pragma unroll
  for (int u = 0; u < SVPT; ++u) {
    int i = base + u * 256;
    bb[u] = -1;
    if (i < tot) {
      int s, d;
      if (i < E) { s = ei[i]; d = ei[E + i]; }
      else       { s = d = i - E; }
      int b = d >> 8;
      bb[u] = b;
      ll[u] = atomicAdd(&lc[b], 1);
      pk[u] = (unsigned)s | ((unsigned)(d & 255) << 16);
    }
  }
  __syncthreads();
  if (lc[t]) lbase[t] = excl + atomicAdd(&bcur_rel[t], lc[t]);
  __syncthreads();
#pragma unroll
  for (int u = 0; u < SVPT; ++u)
    if (bb[u] >= 0) entries[lbase[bb[u]] + ll[u]] = pk[u];
}

// ---------------- D3: csr_build at 1024 threads ----------------

__global__ __launch_bounds__(1024) void csr_build_kernel(const unsigned* __restrict__ entries,
                                                         const int* __restrict__ bcnt,
                                                         int* __restrict__ off,
                                                         unsigned short* __restrict__ eps,
                                                         int n, int B) {
  __shared__ int bscan[256];
  __shared__ int hist[256];
  __shared__ int scn[256];
  __shared__ int cur[256];
  int b = blockIdx.x, t = threadIdx.x;
  if (t < 256) bscan[t] = (t < B) ? bcnt[t] : 0;
  __syncthreads();
  for (int s = 1; s < 256; s <<= 1) {
    int a = (t >= (unsigned)s && t < 256) ? bscan[t - s] : 0;
    __syncthreads();
    if (t < 256) bscan[t] += a;
    __syncthreads();
  }
  int k0 = (b == 0) ? 0 : bscan[b - 1];
  int k1 = bscan[b];

  if (t < 256) hist[t] = 0;
  __syncthreads();
  for (int k = k0 + t; k < k1; k += 1024) atomicAdd(&hist[(entries[k] >> 16) & 255], 1);
  __syncthreads();
  int hv = (t < 256) ? hist[t] : 0;
  if (t < 256) scn[t] = hv;
  __syncthreads();
  for (int s = 1; s < 256; s <<= 1) {
    int a = (t >= (unsigned)s && t < 256) ? scn[t - s] : 0;
    __syncthreads();
    if (t < 256) scn[t] += a;
    __syncthreads();
  }
  if (t < 256) {
    int excl = scn[t] - hv;
    int d = (b << 8) + t;
    if (d < n) off[d] = k0 + excl;
    cur[t] = k0 + excl;
  }
  __syncthreads();
  for (int k = k0 + t; k < k1; k += 1024) {
    unsigned e = entries[k];
    unsigned dl = (e >> 16) & 255;
    int p = atomicAdd(&cur[dl], 1);
    eps[p] = (unsigned short)(e & 0xffffu);
  }
}

// ---------------- D4: agg1 (2 edges per wave-load) ----------------

__global__ __launch_bounds__(256) void agg1_kernel(const unsigned char* __restrict__ Hb8,
                                                   const float2* __restrict__ als,
                                                   const float2* __restrict__ ald,
                                                   const unsigned short* __restrict__ eps,
                                                   const int* __restrict__ off,
                                                   const float* __restrict__ b1,
                                                   const float* __restrict__ vsrc2,
                                                   const float* __restrict__ vdst2,
                                                   const float* __restrict__ vlin,
                                                   float2* __restrict__ gsrc,
                                                   float* __restrict__ adst2, int n) {
  __shared__ float wlds[4][128];
  int wid = (blockIdx.x * 256 + threadIdx.x) >> 6;
  int lane = threadIdx.x & 63;
  if (wid >= n) return;
  wid = __builtin_amdgcn_readfirstlane(wid);
  int wslot = (threadIdx.x >> 6) & 3;
  int sel = lane >> 5;      // which edge of the pair this half-wave handles
  int c31 = lane & 31;      // dword (4 fp8 ch) within the row
  int head = c31 >> 4;      // head of these channels
  int k0 = off[wid], k1 = off[wid + 1];
  const unsigned* Hd = (const unsigned*)Hb8;  // row = 32 dwords
  float2 advv = ald[wid];
  int wbase = head * 64 + sel;  // LDS weight index base

  float a0 = 0.f, a1 = 0.f, a2 = 0.f, a3 = 0.f, den0 = 0.f, den1 = 0.f;

  for (int kb = k0; kb < k1; kb += 64) {
    int rem = min(k1 - kb, 64);
    int e = kb + (lane < rem ? lane : rem - 1);
    unsigned pp = eps[e];
    float2 l = als[pp];
    float g0 = __expf(LEAKY(l.x + advv.x));
    float g1 = __expf(LEAKY(l.y + advv.y));
    bool ok = lane < rem;
    wlds[wslot][lane] = ok ? g0 : 0.f;       // phantom edges get w = 0
    wlds[wslot][64 + lane] = ok ? g1 : 0.f;
    if (ok) { den0 += g0; den1 += g1; }
    int npair = (rem + 1) >> 1;

#define PAIR1(qq)                                                                   \
  {                                                                                 \
    unsigned p = (unsigned)__shfl((int)pp, ((qq) << 1) + sel, 64);                  \
    float w = wlds[wslot][wbase + ((qq) << 1)];                                     \
    unsigned hv = Hd[p * 32u + (unsigned)c31];                                      \
    v2f lo = __builtin_amdgcn_cvt_pk_f32_fp8((int)hv, false);                       \
    v2f hi = __builtin_amdgcn_cvt_pk_f32_fp8((int)hv, true);                        \
    a0 = fmaf(lo.x, w, a0);                                                         \
    a1 = fmaf(lo.y, w, a1);                                                         \
    a2 = fmaf(hi.x, w, a2);                                                         \
    a3 = fmaf(hi.y, w, a3);                                                         \
  }

    int nb = npair >> 3;
    for (int b = 0; b < nb; ++b) {
      int qb = b << 3;
#pragma unroll
      for (int q = 0; q < 8; ++q) PAIR1(qb + q);
    }
    for (int q = nb << 3; q < npair; ++q) PAIR1(q);
#undef PAIR1
  }

  // merge the two edge-sets (halves computed disjoint edges, same channels)
  a0 += __shfl_xor(a0, 32, 64);
  a1 += __shfl_xor(a1, 32, 64);
  a2 += __shfl_xor(a2, 32, 64);
  a3 += __shfl_xor(a3, 32, 64);
  // den butterfly (per-lane partials over distinct edges)
#pragma unroll
  for (int m = 1; m <= 32; m <<= 1) {
    den0 += __shfl_xor(den0, m, 64);
    den1 += __shfl_xor(den1, m, 64);
  }
  float den = head ? den1 : den0;

  // elu(out + b1), then project onto the three layer-2 vectors (4 ch/lane).
  float inv = 1.f / (den + 1e-16f);
  float4 bv = ((const float4*)b1)[c31];
  float r0 = a0 * inv + bv.x;
  float r1 = a1 * inv + bv.y;
  float r2 = a2 * inv + bv.z;
  float r3 = a3 * inv + bv.w;
  r0 = r0 > 0.f ? r0 : (__expf(r0) - 1.f);
  r1 = r1 > 0.f ? r1 : (__expf(r1) - 1.f);
  r2 = r2 > 0.f ? r2 : (__expf(r2) - 1.f);
  r3 = r3 > 0.f ? r3 : (__expf(r3) - 1.f);
  float4 vs = ((const float4*)vsrc2)[c31];
  float4 vd = ((const float4*)vdst2)[c31];
  float4 vl = ((const float4*)vlin)[c31];
  float ps = r0 * vs.x + r1 * vs.y + r2 * vs.z + r3 * vs.w;
  float pd = r0 * vd.x + r1 * vd.y + r2 * vd.z + r3 * vd.w;
  float sv = r0 * vl.x + r1 * vl.y + r2 * vl.z + r3 * vl.w;
  // channels live once per 32-lane half (halves duplicate) -> xor 1..16 only
#pragma unroll
  for (int m = 1; m <= 16; m <<= 1) {
    ps += __shfl_xor(ps, m, 64);
    pd += __shfl_xor(pd, m, 64);
    sv += __shfl_xor(sv, m, 64);
  }
  if (lane == 0) {
    gsrc[wid] = make_float2(ps, sv);
    adst2[wid] = pd;
  }
}

// ---------------- D5: agg2 ----------------

__global__ __launch_bounds__(256) void agg2_kernel(const float2* __restrict__ gsrc,
                                                   const float* __restrict__ adst2,
                                                   const unsigned short* __restrict__ eps,
                                                   const int* __restrict__ off,
                                                   const float* __restrict__ b2,
                                                   const float* __restrict__ lin_w,
                                                   const float* __restrict__ lin_b,
                                                   float* __restrict__ out, int n) {
  int wid = (blockIdx.x * 256 + threadIdx.x) >> 6;
  int lane = threadIdx.x & 63;
  if (wid >= n) return;
  wid = __builtin_amdgcn_readfirstlane(wid);
  int k0 = off[wid], k1 = off[wid + 1];
  float adv = adst2[wid];

  float num = 0.f, den = 0.f;
  for (int kb = k0; kb < k1; kb += 64) {
    int e = kb + lane;
    bool ok = e < k1;
    unsigned pp = eps[ok ? e : k0];
    float2 g = gsrc[pp];
    float w = ok ? __expf(LEAKY(g.x + adv)) : 0.f;
    num = fmaf(w, g.y, num);
    den += w;
  }
  float bt = b2[lane] * lin_w[lane];
#pragma unroll
  for (int m = 1; m <= 32; m <<= 1) {
    num += __shfl_xor(num, m, 64);
    den += __shfl_xor(den, m, 64);
    bt  += __shfl_xor(bt, m, 64);
  }
  if (lane == 0) out[wid] = num / (den + 1e-16f) + bt + lin_b[0];
}

// ---------------- launcher ----------------

static inline size_t alignup(size_t v) { return (v + 255) & ~(size_t)255; }

extern "C" void kernel_launch(void* const* d_in, const int* in_sizes, int n_in,
                              void* d_out, int out_size, void* d_ws, size_t ws_size,
                              hipStream_t stream) {
  const float* x   = (const float*)d_in[0];
  const int*   ei  = (const int*)d_in[1];
  const float* W1  = (const float*)d_in[2];
  const float* as1 = (const float*)d_in[3];
  const float* ad1 = (const float*)d_in[4];
  const float* b1  = (const float*)d_in[5];
  const float* W2  = (const float*)d_in[6];
  const float* as2 = (const float*)d_in[7];
  const float* ad2 = (const float*)d_in[8];
  const float* b2  = (const float*)d_in[9];
  const float* lw  = (const float*)d_in[10];
  const float* lb  = (const float*)d_in[11];
  float* out = (float*)d_out;

  const int N = out_size;          // 50000
  const int E = in_sizes[1] / 2;   // 1600000
  const int Etot = E + N;
  const int B = (N + 255) >> 8;    // 196 buckets

  char* p = (char*)d_ws;
  int* bcnt = (int*)p;  p += alignup((size_t)(B + 1) * 4);
  int* bcur_rel = (int*)p; p += alignup((size_t)(B + 1) * 4);
  unsigned* entries = (unsigned*)p; p += alignup((size_t)Etot * 4);
  int* off  = (int*)p;  p += alignup((size_t)(N + 1) * 4);
  unsigned short* eps = (unsigned short*)p; p += alignup((size_t)Etot * 2);
  float2* als = (float2*)p; p += alignup((size_t)N * 8);
  float2* ald = (float2*)p; p += alignup((size_t)N * 8);
  float2* gsrc = (float2*)p; p += alignup((size_t)N * 8);
  float* adst2 = (float*)p; p += alignup((size_t)N * 4);
  unsigned char* h1b = (unsigned char*)p; p += alignup((size_t)N * 128);
  unsigned short* wp1 = (unsigned short*)p; p += alignup((size_t)16384 * 2);
  float* vsrc2 = (float*)p; p += alignup((size_t)128 * 4);
  float* vdst2 = (float*)p; p += alignup((size_t)128 * 4);
  float* vlin  = (float*)p; p += alignup((size_t)128 * 4);

  constexpr int VPT = 8;    // bucket_cnt edges/thread
  constexpr int SVPT = 16;  // bucket_scatter edges/thread (measured optimum)
  int egrid = (Etot + 256 * VPT - 1) / (256 * VPT);
  int sgrid = (Etot + 256 * SVPT - 1) / (256 * SVPT);
  constexpr int WB = 65;                 // wprep blocks
  int GB = (N + 31) / 32;                // gemm1 blocks

  zero_kernel<<<1, 256, 0, stream>>>(bcnt, bcur_rel, off, B, N, Etot);
  prep_cnt_kernel<VPT><<<WB + egrid, 256, 0, stream>>>(
      W1, W2, as2, ad2, lw, wp1, vsrc2, vdst2, vlin, ei, E, N, bcnt, WB);
  gemm_scatter_kernel<SVPT><<<GB + sgrid, 256, 0, stream>>>(
      x, (const uint4*)wp1, as1, ad1, h1b, als, ald,
      ei, E, N, bcnt, bcur_rel, entries, B, GB);
  csr_build_kernel<<<B, 1024, 0, stream>>>(entries, bcnt, off, eps, N, B);

  agg1_kernel<<<(N + 3) / 4, 256, 0, stream>>>(h1b, als, ald, eps, off, b1,
                                               vsrc2, vdst2, vlin, gsrc, adst2, N);
  agg2_kernel<<<(N + 3) / 4, 256, 0, stream>>>(gsrc, adst2, eps, off, b2, lw, lb, out, N);
}